// Round 6
// baseline (677.112 us; speedup 1.0000x reference)
//
#include <hip/hip_runtime.h>
#include <hip/hip_bf16.h>
#include <math.h>

#define S 1024
#define D 1024
#define P 2816
#define R 64
#define E 8
#define M 16
#define NBLK 512
#define KSPLIT 4
#define KQ (P / KSPLIT)   // 704
#define NIT (KQ / 64)     // 11

typedef __attribute__((ext_vector_type(8))) short short8;   // 8 bf16
typedef __attribute__((ext_vector_type(4))) float floatx4;  // MFMA acc

static __device__ inline unsigned short f2bf(float f) {
  __hip_bfloat16 h = __float2bfloat16(f);
  return *reinterpret_cast<unsigned short*>(&h);
}

typedef unsigned short (*Row72)[72];
typedef unsigned short (*Row136)[136];

// Self-initializing grid barrier: each block stores ONLY its own slot
// (device-scope release), then all threads watch 2 slots each.
// Poison 0xAAAAAAAA is negative -> "< target" until written this call.
// Stale values (3) from an unpoisoned profiler replay pass instantly -> no
// deadlock; bounded spin is a last-resort failsafe.
static __device__ inline void gridbar(int* slots, int target) {
  __syncthreads();
  if (threadIdx.x == 0) {
    __threadfence();  // make this block's prior writes visible device-wide
    __hip_atomic_store(&slots[blockIdx.x], target, __ATOMIC_RELEASE,
                       __HIP_MEMORY_SCOPE_AGENT);
  }
#pragma unroll
  for (int j = 0; j < 2; ++j) {
    int s = threadIdx.x + j * 256;
    int spins = 0;
    while (__hip_atomic_load(&slots[s], __ATOMIC_ACQUIRE,
                             __HIP_MEMORY_SCOPE_AGENT) < target) {
      __builtin_amdgcn_s_sleep(2);
      if (++spins > 2000000) break;  // failsafe (replay-only path)
    }
  }
  __threadfence();
  __syncthreads();
}

__global__ __launch_bounds__(256, 2) void k_fused(
    const float* __restrict__ H, const int* __restrict__ idx,
    const float* __restrict__ wts, const float* __restrict__ Aup,
    const float* __restrict__ Agate, const float* __restrict__ upl,
    const float* __restrict__ gatel, const float* __restrict__ Wd,
    const float* __restrict__ upb, const float* __restrict__ gateb,
    unsigned short* __restrict__ mxu, unsigned short* __restrict__ mxg,
    float* __restrict__ tbuf32, unsigned short* __restrict__ inter,
    int* __restrict__ perm, int* __restrict__ offs, int* __restrict__ slots,
    float* __restrict__ out) {
  // LDS union: P1 As(9216)+Bs(18432)=27648; P2 Ts(34816)+Bu(9216)+Bg(9216)=53248;
  // P3 As(36864)+Bs(9216)=46080. Max 53248 B -> 2 blocks/CU (104 KB/CU).
  __shared__ __align__(16) char smem[53248];
  __shared__ float alphabuf[2][E][M];
  __shared__ int hist[E];
  __shared__ int basearr[E];

  const int b = blockIdx.x;
  const int t = threadIdx.x;
  const int lane = t & 63, w = t >> 6, quad = lane >> 4, l15 = lane & 15;

  // ======================= P0: zero + mix + sort =======================
  {
    // zero out: 512 blocks x 2048 floats
    float4 z4 = make_float4(0.f, 0.f, 0.f, 0.f);
    *(float4*)(out + (size_t)b * 2048 + t * 8) = z4;
    *(float4*)(out + (size_t)b * 2048 + t * 8 + 4) = z4;
    // zero tbuf32: 512 blocks x 256 floats
    tbuf32[(size_t)b * 256 + t] = 0.f;

    if (b == 300) {  // counting sort, 4 tokens/thread
      if (t < E) hist[t] = 0;
      __syncthreads();
      int e4[4];
#pragma unroll
      for (int j = 0; j < 4; ++j) {
        e4[j] = idx[t + j * 256];
        atomicAdd(&hist[e4[j]], 1);
      }
      __syncthreads();
      if (t == 0) {
        int run = 0;
        for (int i = 0; i < E; ++i) { basearr[i] = run; offs[i] = run; run += hist[i]; }
        offs[E] = S;
      }
      __syncthreads();
#pragma unroll
      for (int j = 0; j < 4; ++j) {
        int pos = atomicAdd(&basearr[e4[j]], 1);
        perm[pos] = t + j * 256;
      }
    }

    if (b >= 1 && b < 257) {  // mix: 256 slices
      int mb = b - 1;
      if (t < 16) {
        int mat = t >> 3, e = t & 7;
        const float* lg = (mat ? gatel : upl) + e * M;
        float v[M], mx = -1e30f, s = 0.f;
#pragma unroll
        for (int m = 0; m < M; ++m) { v[m] = lg[m]; mx = fmaxf(mx, v[m]); }
#pragma unroll
        for (int m = 0; m < M; ++m) { v[m] = expf(v[m] - mx); s += v[m]; }
#pragma unroll
        for (int m = 0; m < M; ++m) alphabuf[mat][e][m] = v[m] / s;
      }
      __syncthreads();
      int g = mb * 256 + t;
      int d = g >> 6, r = g & 63;
      float au[E] = {0, 0, 0, 0, 0, 0, 0, 0}, ag[E] = {0, 0, 0, 0, 0, 0, 0, 0};
#pragma unroll
      for (int m = 0; m < M; ++m) {
        float vu = upb[((size_t)m * D + d) * R + r];
        float vg = gateb[((size_t)m * D + d) * R + r];
#pragma unroll
        for (int e = 0; e < E; ++e) {
          au[e] += alphabuf[0][e][m] * vu;
          ag[e] += alphabuf[1][e][m] * vg;
        }
      }
#pragma unroll
      for (int e = 0; e < E; ++e) {
        mxu[((size_t)e * D + d) * R + r] = f2bf(au[e]);
        mxg[((size_t)e * D + d) * R + r] = f2bf(ag[e]);
      }
    }
  }
  gridbar(slots, 1);

  // ======================= P1: t = H @ [mxu|mxg] =======================
  {
    int e = b & 7, y = (b >> 3) & 3, z = b >> 5;  // 8 x 4 x 16
    int start = offs[e] + y * 64;
    int end = offs[e + 1];
    if (start < end) {
      Row72 As = (Row72)smem;                 // 64 x 72
      Row72 Bs = (Row72)(smem + 9216);        // 128 x 72
      int k0 = z * 64;
      // A-stage: 64 tok x 64 k, fp32 gather -> bf16; 2 chunks/thread
#pragma unroll
      for (int j = 0; j < 2; ++j) {
        int c = t + j * 256;
        int arow = c >> 3, acol = (c & 7) * 8;
        int pos = start + arow;
        short8 v = (short8){0, 0, 0, 0, 0, 0, 0, 0};
        if (pos < end) {
          const float* src = H + (size_t)perm[pos] * D + k0 + acol;
          float4 f0 = *(const float4*)src;
          float4 f1 = *(const float4*)(src + 4);
          v[0] = f2bf(f0.x); v[1] = f2bf(f0.y); v[2] = f2bf(f0.z); v[3] = f2bf(f0.w);
          v[4] = f2bf(f1.x); v[5] = f2bf(f1.y); v[6] = f2bf(f1.z); v[7] = f2bf(f1.w);
        }
        *(short8*)&As[arow][acol] = v;
      }
      // B-stage transpose: mixed[e][k][r] -> Bs[r(u)|64+r(g)][k_local]
      {
        int dd = t >> 2, r0 = (t & 3) * 16;
        const unsigned short* su = mxu + ((size_t)e * D + k0 + dd) * R + r0;
        const unsigned short* sg = mxg + ((size_t)e * D + k0 + dd) * R + r0;
        short8 u0 = *(const short8*)su, u1 = *(const short8*)(su + 8);
        short8 g0 = *(const short8*)sg, g1 = *(const short8*)(sg + 8);
#pragma unroll
        for (int j = 0; j < 8; ++j) {
          Bs[r0 + j][dd] = u0[j];
          Bs[r0 + 8 + j][dd] = u1[j];
          Bs[64 + r0 + j][dd] = g0[j];
          Bs[64 + r0 + 8 + j][dd] = g1[j];
        }
      }
      __syncthreads();
      floatx4 acc[8];
#pragma unroll
      for (int nt = 0; nt < 8; ++nt) acc[nt] = (floatx4){0.f, 0.f, 0.f, 0.f};
#pragma unroll
      for (int ks = 0; ks < 2; ++ks) {
        int kc = ks * 32 + quad * 8;
        short8 a = *(const short8*)&As[w * 16 + l15][kc];
#pragma unroll
        for (int nt = 0; nt < 8; ++nt) {
          short8 bb = *(const short8*)&Bs[nt * 16 + l15][kc];
          acc[nt] = __builtin_amdgcn_mfma_f32_16x16x32_bf16(a, bb, acc[nt], 0, 0, 0);
        }
      }
#pragma unroll
      for (int reg = 0; reg < 4; ++reg) {
        int pos = start + w * 16 + quad * 4 + reg;
        if (pos < end) {
#pragma unroll
          for (int nt = 0; nt < 8; ++nt)
            atomicAdd(&tbuf32[(size_t)pos * 128 + nt * 16 + l15], acc[nt][reg]);
        }
      }
    }
  }
  gridbar(slots, 2);

  // ======================= P2: inter = silu(gate)*up =======================
  {
    Row136 Ts = (Row136)smem;               // 128 x 136
    Row72 Bu = (Row72)(smem + 34816);       // 64 x 72
    Row72 Bg = (Row72)(smem + 44032);       // 64 x 72
    for (int u = b; u < 704; u += NBLK) {
      int e = u & 7, rest = u >> 3;
      int yt = rest & 1, pc = rest >> 1;    // 2 tok-tiles x 44 p-chunks
      int start = offs[e] + yt * 128;
      int end = offs[e + 1];
      if (start >= end) continue;
      int p0 = pc * 64;
      // stage T: 128 x 128 fp32 -> bf16; 8 chunks/thread
#pragma unroll
      for (int j = 0; j < 8; ++j) {
        int i = t + j * 256;
        int row = i >> 4, c8 = (i & 15) * 8;
        int pos = start + row;
        short8 v = (short8){0, 0, 0, 0, 0, 0, 0, 0};
        if (pos < end) {
          const float* src = tbuf32 + (size_t)pos * 128 + c8;
          float4 f0 = *(const float4*)src;
          float4 f1 = *(const float4*)(src + 4);
          v[0] = f2bf(f0.x); v[1] = f2bf(f0.y); v[2] = f2bf(f0.z); v[3] = f2bf(f0.w);
          v[4] = f2bf(f1.x); v[5] = f2bf(f1.y); v[6] = f2bf(f1.z); v[7] = f2bf(f1.w);
        }
        *(short8*)&Ts[row][c8] = v;
      }
      // stage Bu/Bg: 64p x 64r fp32 -> bf16; 2 chunks/thread each
#pragma unroll
      for (int j = 0; j < 2; ++j) {
        int i = t + j * 256;
        int pr = i >> 3, c8 = (i & 7) * 8;
        const float* su = Aup + ((size_t)(e * P + p0 + pr) * R + c8);
        const float* sg = Agate + ((size_t)(e * P + p0 + pr) * R + c8);
        float4 u0 = *(const float4*)su, u1 = *(const float4*)(su + 4);
        float4 g0 = *(const float4*)sg, g1 = *(const float4*)(sg + 4);
        short8 uv, gv;
        uv[0] = f2bf(u0.x); uv[1] = f2bf(u0.y); uv[2] = f2bf(u0.z); uv[3] = f2bf(u0.w);
        uv[4] = f2bf(u1.x); uv[5] = f2bf(u1.y); uv[6] = f2bf(u1.z); uv[7] = f2bf(u1.w);
        gv[0] = f2bf(g0.x); gv[1] = f2bf(g0.y); gv[2] = f2bf(g0.z); gv[3] = f2bf(g0.w);
        gv[4] = f2bf(g1.x); gv[5] = f2bf(g1.y); gv[6] = f2bf(g1.z); gv[7] = f2bf(g1.w);
        *(short8*)&Bu[pr][c8] = uv;
        *(short8*)&Bg[pr][c8] = gv;
      }
      __syncthreads();
      floatx4 au_acc[2][4], ag_acc[2][4];
#pragma unroll
      for (int tt = 0; tt < 2; ++tt)
#pragma unroll
        for (int pt = 0; pt < 4; ++pt) {
          au_acc[tt][pt] = (floatx4){0.f, 0.f, 0.f, 0.f};
          ag_acc[tt][pt] = (floatx4){0.f, 0.f, 0.f, 0.f};
        }
#pragma unroll
      for (int kh = 0; kh < 2; ++kh) {
        int kc = kh * 32 + quad * 8;
        short8 au[2], ag[2], bu[4], bg[4];
#pragma unroll
        for (int tt = 0; tt < 2; ++tt) {
          au[tt] = *(const short8*)&Ts[w * 32 + tt * 16 + l15][kc];
          ag[tt] = *(const short8*)&Ts[w * 32 + tt * 16 + l15][64 + kc];
        }
#pragma unroll
        for (int pt = 0; pt < 4; ++pt) {
          bu[pt] = *(const short8*)&Bu[pt * 16 + l15][kc];
          bg[pt] = *(const short8*)&Bg[pt * 16 + l15][kc];
        }
#pragma unroll
        for (int tt = 0; tt < 2; ++tt)
#pragma unroll
          for (int pt = 0; pt < 4; ++pt) {
            au_acc[tt][pt] = __builtin_amdgcn_mfma_f32_16x16x32_bf16(au[tt], bu[pt], au_acc[tt][pt], 0, 0, 0);
            ag_acc[tt][pt] = __builtin_amdgcn_mfma_f32_16x16x32_bf16(ag[tt], bg[pt], ag_acc[tt][pt], 0, 0, 0);
          }
      }
#pragma unroll
      for (int tt = 0; tt < 2; ++tt)
#pragma unroll
        for (int reg = 0; reg < 4; ++reg) {
          int row = w * 32 + tt * 16 + quad * 4 + reg;
          int pos = start + row;
          if (pos < end) {
#pragma unroll
            for (int pt = 0; pt < 4; ++pt) {
              float g = ag_acc[tt][pt][reg];
              float uu = au_acc[tt][pt][reg];
              float val = uu * (g / (1.f + __expf(-g)));
              inter[(size_t)pos * P + p0 + pt * 16 + l15] = f2bf(val);
            }
          }
        }
      __syncthreads();  // LDS reuse across stride iterations
    }
  }
  gridbar(slots, 3);

  // ======================= P3: down GEMM + scatter =======================
  {
    int e = b & 7, kz = (b >> 3) & 3, dz = b >> 5;  // 8 x 4 x 16
    int start = offs[e];
    int end = offs[e + 1];
    if (start < end) {
      Row72 As = (Row72)smem;                // 256 x 72
      Row72 Bs = (Row72)(smem + 36864);      // 64 x 72
      int d0 = dz * 64;
      const unsigned short* aptr[8];
      bool aok[8];
#pragma unroll
      for (int j = 0; j < 8; ++j) {
        int arow = (t >> 3) + 32 * j;
        int pos = start + arow;
        aok[j] = (pos < end);
        aptr[j] = inter + (size_t)(aok[j] ? pos : start) * P + kz * KQ + (t & 7) * 8;
      }
      const float* bsrc = Wd + ((size_t)(e * D + d0 + (t >> 2)) * P + kz * KQ + (t & 3) * 16);

      float4 pa[8];
      float4 pb[4];
#pragma unroll
      for (int j = 0; j < 8; ++j)
        pa[j] = aok[j] ? *(const float4*)(aptr[j]) : make_float4(0.f, 0.f, 0.f, 0.f);
#pragma unroll
      for (int q = 0; q < 4; ++q) pb[q] = *(const float4*)(bsrc + q * 4);

      floatx4 acc[4][4];
#pragma unroll
      for (int tt = 0; tt < 4; ++tt)
#pragma unroll
        for (int dt = 0; dt < 4; ++dt) acc[tt][dt] = (floatx4){0.f, 0.f, 0.f, 0.f};

      for (int it = 0; it < NIT; ++it) {
#pragma unroll
        for (int j = 0; j < 8; ++j)
          *(float4*)&As[(t >> 3) + 32 * j][(t & 7) * 8] = pa[j];
        {
          short8 bv0, bv1;
          bv0[0] = f2bf(pb[0].x); bv0[1] = f2bf(pb[0].y); bv0[2] = f2bf(pb[0].z); bv0[3] = f2bf(pb[0].w);
          bv0[4] = f2bf(pb[1].x); bv0[5] = f2bf(pb[1].y); bv0[6] = f2bf(pb[1].z); bv0[7] = f2bf(pb[1].w);
          bv1[0] = f2bf(pb[2].x); bv1[1] = f2bf(pb[2].y); bv1[2] = f2bf(pb[2].z); bv1[3] = f2bf(pb[2].w);
          bv1[4] = f2bf(pb[3].x); bv1[5] = f2bf(pb[3].y); bv1[6] = f2bf(pb[3].z); bv1[7] = f2bf(pb[3].w);
          *(short8*)&Bs[t >> 2][(t & 3) * 16] = bv0;
          *(short8*)&Bs[t >> 2][(t & 3) * 16 + 8] = bv1;
        }
        __syncthreads();
        if (it + 1 < NIT) {
          int k0 = (it + 1) * 64;
#pragma unroll
          for (int j = 0; j < 8; ++j)
            pa[j] = aok[j] ? *(const float4*)(aptr[j] + k0) : make_float4(0.f, 0.f, 0.f, 0.f);
#pragma unroll
          for (int q = 0; q < 4; ++q) pb[q] = *(const float4*)(bsrc + k0 + q * 4);
        }
#pragma unroll
        for (int ks = 0; ks < 2; ++ks) {
          int kc = ks * 32 + quad * 8;
          short8 a[4], bb[4];
#pragma unroll
          for (int tt = 0; tt < 4; ++tt) a[tt] = *(const short8*)&As[w * 64 + tt * 16 + l15][kc];
#pragma unroll
          for (int dt = 0; dt < 4; ++dt) bb[dt] = *(const short8*)&Bs[dt * 16 + l15][kc];
#pragma unroll
          for (int tt = 0; tt < 4; ++tt)
#pragma unroll
            for (int dt = 0; dt < 4; ++dt)
              acc[tt][dt] = __builtin_amdgcn_mfma_f32_16x16x32_bf16(a[tt], bb[dt], acc[tt][dt], 0, 0, 0);
        }
        __syncthreads();
      }
#pragma unroll
      for (int tt = 0; tt < 4; ++tt)
#pragma unroll
        for (int reg = 0; reg < 4; ++reg) {
          int pos = start + w * 64 + tt * 16 + quad * 4 + reg;
          if (pos < end) {
            int tok = perm[pos];
            float wt = wts[tok];
#pragma unroll
            for (int dt = 0; dt < 4; ++dt)
              atomicAdd(&out[(size_t)tok * D + d0 + dt * 16 + l15], acc[tt][dt][reg] * wt);
          }
        }
    }
  }
}

// ---------------------------------------------------------------------------
extern "C" void kernel_launch(void* const* d_in, const int* in_sizes, int n_in,
                              void* d_out, int out_size, void* d_ws, size_t ws_size,
                              hipStream_t stream) {
  const float* H = (const float*)d_in[0];
  const int* idx = (const int*)d_in[1];
  const float* wts = (const float*)d_in[2];
  const float* Aup = (const float*)d_in[3];
  const float* Agate = (const float*)d_in[4];
  const float* upl = (const float*)d_in[5];
  const float* gatel = (const float*)d_in[6];
  const float* Wd = (const float*)d_in[7];
  const float* upb = (const float*)d_in[8];
  const float* gateb = (const float*)d_in[9];
  float* out = (float*)d_out;

  char* ws = (char*)d_ws;
  unsigned short* mxu = (unsigned short*)ws;                 // E*D*R bf16 = 1 MB
  unsigned short* mxg = mxu + (size_t)E * D * R;             // 1 MB
  float* tbuf32 = (float*)(mxg + (size_t)E * D * R);         // S*128 f32 = 512 KB
  unsigned short* inter = (unsigned short*)(tbuf32 + (size_t)S * 128);  // S*P bf16
  int* perm = (int*)(inter + (size_t)S * P);                 // S
  int* offs = perm + S;                                      // E+1
  int* slots = offs + 16;                                    // NBLK (aligned region)

  k_fused<<<NBLK, 256, 0, stream>>>(H, idx, wts, Aup, Agate, upl, gatel, Wd,
                                    upb, gateb, mxu, mxg, tbuf32, inter, perm,
                                    offs, slots, out);
}